// Round 1
// baseline (432.945 us; speedup 1.0000x reference)
//
#include <hip/hip_runtime.h>
#include <hip/hip_bf16.h>
#include <cstdint>
#include <cstddef>

typedef __attribute__((ext_vector_type(8))) short short8;
typedef __attribute__((ext_vector_type(4))) float floatx4;
typedef unsigned short u16;

__device__ __forceinline__ u16 f2bf(float f) {
  unsigned u = __float_as_uint(f);
  u += 0x7FFFu + ((u >> 16) & 1u);
  return (u16)(u >> 16);
}

// ---------------- f32 -> bf16 convert (vectorized) ----------------
__global__ void cvt_kernel(const float* __restrict__ in, u16* __restrict__ out, int n4) {
  int i = blockIdx.x * blockDim.x + threadIdx.x;
  int stride = gridDim.x * blockDim.x;
  for (int idx = i; idx < n4; idx += stride) {
    float4 v = reinterpret_cast<const float4*>(in)[idx];
    ushort4 o = make_ushort4(f2bf(v.x), f2bf(v.y), f2bf(v.z), f2bf(v.w));
    reinterpret_cast<ushort4*>(out)[idx] = o;
  }
}

// ---------------- C = A @ B^T + bias ----------------
// A[M,K] bf16 row-major, B[N,K] bf16 row-major. 64x64 tile, 4 waves (2x2),
// BK=32, mfma_f32_16x16x32_bf16. LDS stride 40 (80B = 16B-aligned, 2-way banks).
template<bool OUTF32>
__global__ __launch_bounds__(256) void gemm_bt(
    const u16* __restrict__ A, const u16* __restrict__ B,
    const float* __restrict__ bias, void* __restrict__ Cout,
    int M, int N, int K)
{
  constexpr int LDT = 40;
  __shared__ u16 As[64 * LDT];
  __shared__ u16 Bs[64 * LDT];
  const int tid = threadIdx.x;
  const int lane = tid & 63, wave = tid >> 6;
  const int l15 = lane & 15, lhi = lane >> 4;
  const int wm = wave >> 1, wn = wave & 1;
  const int m0 = blockIdx.x * 64, n0 = blockIdx.y * 64;
  const int srow = tid >> 2, scol = (tid & 3) * 8;

  const u16* aptr = A + (size_t)(m0 + srow) * K + scol;
  const u16* bptr = B + (size_t)(n0 + srow) * K + scol;

  floatx4 acc[2][2] = {};

  for (int k0 = 0; k0 < K; k0 += 32) {
    short8 av = *reinterpret_cast<const short8*>(aptr + k0);
    short8 bv = *reinterpret_cast<const short8*>(bptr + k0);
    __syncthreads();
    *reinterpret_cast<short8*>(&As[srow * LDT + scol]) = av;
    *reinterpret_cast<short8*>(&Bs[srow * LDT + scol]) = bv;
    __syncthreads();
    short8 af[2], bfr[2];
#pragma unroll
    for (int f = 0; f < 2; ++f) {
      af[f]  = *reinterpret_cast<const short8*>(&As[(wm * 32 + f * 16 + l15) * LDT + lhi * 8]);
      bfr[f] = *reinterpret_cast<const short8*>(&Bs[(wn * 32 + f * 16 + l15) * LDT + lhi * 8]);
    }
#pragma unroll
    for (int i = 0; i < 2; ++i)
#pragma unroll
      for (int j = 0; j < 2; ++j)
        acc[i][j] = __builtin_amdgcn_mfma_f32_16x16x32_bf16(af[i], bfr[j], acc[i][j], 0, 0, 0);
  }

#pragma unroll
  for (int i = 0; i < 2; ++i)
#pragma unroll
    for (int j = 0; j < 2; ++j) {
      int row = m0 + wm * 32 + i * 16 + lhi * 4;
      int col = n0 + wn * 32 + j * 16 + l15;
      float bv = bias[col];
#pragma unroll
      for (int r = 0; r < 4; ++r) {
        float v = acc[i][j][r] + bv;
        if (OUTF32) reinterpret_cast<float*>(Cout)[(size_t)(row + r) * N + col] = v;
        else        reinterpret_cast<u16*>(Cout)[(size_t)(row + r) * N + col] = f2bf(v);
      }
    }
}

// ---------------- fused flash attention ----------------
// qkv: [B*S, 2304] bf16 (cols: 0..767 Q, 768..1535 K, 1536..2303 V, each H=12 heads x 64)
// z:   [B*S, 768] bf16 output
// Block: one (b, h, 64-q-row tile). 4 waves x 16 rows each. KV tiles of 64.
__global__ __launch_bounds__(256) void attn_kernel(
    const u16* __restrict__ qkv, u16* __restrict__ z)
{
  constexpr int LDK = 72;
  __shared__ u16 Ks[64 * LDK];    // K rows (keys) x 64 dims
  __shared__ u16 Vts[64 * LDK];   // transposed V: rows = dim, cols = key
  __shared__ u16 Ps[4][16 * LDK]; // per-wave P tile: 16 q-rows x 64 keys

  const int tid = threadIdx.x;
  const int lane = tid & 63, wave = tid >> 6;
  const int l15 = lane & 15, lhi = lane >> 4;

  const int idx = blockIdx.x;
  const int qt = idx & 15;            // S/64 = 16 q tiles
  const int h  = (idx >> 4) % 12;
  const int b  = idx / (16 * 12);

  const size_t rowbase = (size_t)b * 1024;
  const u16* Qp = qkv + rowbase * 2304 + h * 64;
  const u16* Kp = Qp + 768;
  const u16* Vp = Qp + 1536;

  const int qrow = qt * 64 + wave * 16;

  short8 qf[2];
#pragma unroll
  for (int c = 0; c < 2; ++c)
    qf[c] = *reinterpret_cast<const short8*>(Qp + (size_t)(qrow + l15) * 2304 + c * 32 + lhi * 8);

  floatx4 o_acc[4] = {};
  float m_run[4], l_run[4];
#pragma unroll
  for (int j = 0; j < 4; ++j) { m_run[j] = -1e30f; l_run[j] = 0.f; }

  for (int kt = 0; kt < 16; ++kt) {
    const int kv0 = kt * 64;
    __syncthreads();  // previous iteration's reads of Ks/Vts done
#pragma unroll
    for (int i = 0; i < 2; ++i) {
      int id = tid + i * 256;
      int row = id >> 3, c8 = (id & 7) * 8;
      short8 kvv = *reinterpret_cast<const short8*>(Kp + (size_t)(kv0 + row) * 2304 + c8);
      short8 vvv = *reinterpret_cast<const short8*>(Vp + (size_t)(kv0 + row) * 2304 + c8);
      *reinterpret_cast<short8*>(&Ks[row * LDK + c8]) = kvv;
#pragma unroll
      for (int jj = 0; jj < 8; ++jj)
        Vts[(c8 + jj) * LDK + row] = (u16)vvv[jj];
    }
    __syncthreads();

    // S = Q @ K^T  (16 rows x 64 keys per wave)
    floatx4 s[4];
#pragma unroll
    for (int fn = 0; fn < 4; ++fn) {
      floatx4 a = {};
#pragma unroll
      for (int c = 0; c < 2; ++c) {
        short8 kf = *reinterpret_cast<const short8*>(&Ks[(fn * 16 + l15) * LDK + c * 32 + lhi * 8]);
        a = __builtin_amdgcn_mfma_f32_16x16x32_bf16(qf[c], kf, a, 0, 0, 0);
      }
      s[fn] = a;
    }

    // online softmax; row j lives in lanes sharing lhi, spread over l15
    float alpha[4];
#pragma unroll
    for (int j = 0; j < 4; ++j) {
      float v0 = s[0][j] * 0.125f, v1 = s[1][j] * 0.125f;
      float v2 = s[2][j] * 0.125f, v3 = s[3][j] * 0.125f;
      s[0][j] = v0; s[1][j] = v1; s[2][j] = v2; s[3][j] = v3;
      float mx = fmaxf(fmaxf(v0, v1), fmaxf(v2, v3));
#pragma unroll
      for (int d = 1; d < 16; d <<= 1) mx = fmaxf(mx, __shfl_xor(mx, d, 64));
      float mnew = fmaxf(m_run[j], mx);
      float al = __expf(m_run[j] - mnew);
      float sum = 0.f;
#pragma unroll
      for (int fn = 0; fn < 4; ++fn) { float p = __expf(s[fn][j] - mnew); s[fn][j] = p; sum += p; }
#pragma unroll
      for (int d = 1; d < 16; d <<= 1) sum += __shfl_xor(sum, d, 64);
      m_run[j] = mnew; l_run[j] = l_run[j] * al + sum; alpha[j] = al;
    }

    // P -> LDS (bf16), rescale O
#pragma unroll
    for (int j = 0; j < 4; ++j)
#pragma unroll
      for (int fn = 0; fn < 4; ++fn)
        Ps[wave][(lhi * 4 + j) * LDK + fn * 16 + l15] = f2bf(s[fn][j]);
#pragma unroll
    for (int fd = 0; fd < 4; ++fd)
#pragma unroll
      for (int j = 0; j < 4; ++j)
        o_acc[fd][j] *= alpha[j];

    __syncthreads();  // Ps visible (and ordered) for fragment re-read

    // O += P @ V
    short8 pf[2];
#pragma unroll
    for (int c = 0; c < 2; ++c)
      pf[c] = *reinterpret_cast<const short8*>(&Ps[wave][l15 * LDK + c * 32 + lhi * 8]);
#pragma unroll
    for (int fd = 0; fd < 4; ++fd) {
#pragma unroll
      for (int c = 0; c < 2; ++c) {
        short8 vf = *reinterpret_cast<const short8*>(&Vts[(fd * 16 + l15) * LDK + c * 32 + lhi * 8]);
        o_acc[fd] = __builtin_amdgcn_mfma_f32_16x16x32_bf16(pf[c], vf, o_acc[fd], 0, 0, 0);
      }
    }
  }

#pragma unroll
  for (int fd = 0; fd < 4; ++fd)
#pragma unroll
    for (int j = 0; j < 4; ++j) {
      float v = o_acc[fd][j] / l_run[j];
      z[(rowbase + qrow + lhi * 4 + j) * 768 + h * 64 + fd * 16 + l15] = f2bf(v);
    }
}

extern "C" void kernel_launch(void* const* d_in, const int* in_sizes, int n_in,
                              void* d_out, int out_size, void* d_ws, size_t ws_size,
                              hipStream_t stream) {
  (void)in_sizes; (void)n_in; (void)out_size; (void)ws_size;
  const float* x      = (const float*)d_in[0];
  const float* w_qkv  = (const float*)d_in[1];
  const float* b_qkv  = (const float*)d_in[2];
  const float* w_proj = (const float*)d_in[3];
  const float* b_proj = (const float*)d_in[4];
  float* out = (float*)d_out;

  const int BS = 16 * 1024;  // B*S rows
  const int D = 768, N3 = 2304;

  // workspace layout (bf16 buffers), total ~130.5 MB
  u16* xb  = (u16*)d_ws;                     // [BS, D]
  u16* wqb = xb  + (size_t)BS * D;           // [N3, D]
  u16* wpb = wqb + (size_t)N3 * D;           // [D, D]
  u16* qkv = wpb + (size_t)D * D;            // [BS, N3]
  u16* zb  = qkv + (size_t)BS * N3;          // [BS, D]

  cvt_kernel<<<2048, 256, 0, stream>>>(x, xb, BS * D / 4);
  cvt_kernel<<<512, 256, 0, stream>>>(w_qkv, wqb, N3 * D / 4);
  cvt_kernel<<<256, 256, 0, stream>>>(w_proj, wpb, D * D / 4);

  gemm_bt<false><<<dim3(BS / 64, N3 / 64), 256, 0, stream>>>(xb, wqb, b_qkv, qkv, BS, N3, D);
  attn_kernel<<<16 * 12 * 16, 256, 0, stream>>>(qkv, zb);
  gemm_bt<true><<<dim3(BS / 64, D / 64), 256, 0, stream>>>(zb, wpb, b_proj, out, BS, D, D);
}

// Round 2
// 330.686 us; speedup vs baseline: 1.3092x; 1.3092x over previous
//
#include <hip/hip_runtime.h>
#include <hip/hip_bf16.h>
#include <cstdint>
#include <cstddef>

typedef __attribute__((ext_vector_type(8))) short short8;
typedef __attribute__((ext_vector_type(4))) float floatx4;
typedef __attribute__((ext_vector_type(16))) float floatx16;
typedef unsigned short u16;

__device__ __forceinline__ u16 f2bf(float f) {
  unsigned u = __float_as_uint(f);
  u += 0x7FFFu + ((u >> 16) & 1u);
  return (u16)(u >> 16);
}

__device__ __forceinline__ unsigned cvt_pk_bf16(float a, float b) {
  unsigned r;
  asm("v_cvt_pk_bf16_f32 %0, %1, %2" : "=v"(r) : "v"(a), "v"(b));
  return r;
}

// ---------------- f32 -> bf16 convert (vectorized) ----------------
__global__ void cvt_kernel(const float* __restrict__ in, u16* __restrict__ out, int n4) {
  int i = blockIdx.x * blockDim.x + threadIdx.x;
  int stride = gridDim.x * blockDim.x;
  for (int idx = i; idx < n4; idx += stride) {
    float4 v = reinterpret_cast<const float4*>(in)[idx];
    ushort4 o = make_ushort4(f2bf(v.x), f2bf(v.y), f2bf(v.z), f2bf(v.w));
    reinterpret_cast<ushort4*>(out)[idx] = o;
  }
}

// ---------------- C = A @ B^T + bias (unchanged from R1) ----------------
template<bool OUTF32>
__global__ __launch_bounds__(256) void gemm_bt(
    const u16* __restrict__ A, const u16* __restrict__ B,
    const float* __restrict__ bias, void* __restrict__ Cout,
    int M, int N, int K)
{
  constexpr int LDT = 40;
  __shared__ u16 As[64 * LDT];
  __shared__ u16 Bs[64 * LDT];
  const int tid = threadIdx.x;
  const int lane = tid & 63, wave = tid >> 6;
  const int l15 = lane & 15, lhi = lane >> 4;
  const int wm = wave >> 1, wn = wave & 1;
  const int m0 = blockIdx.x * 64, n0 = blockIdx.y * 64;
  const int srow = tid >> 2, scol = (tid & 3) * 8;

  const u16* aptr = A + (size_t)(m0 + srow) * K + scol;
  const u16* bptr = B + (size_t)(n0 + srow) * K + scol;

  floatx4 acc[2][2] = {};

  for (int k0 = 0; k0 < K; k0 += 32) {
    short8 av = *reinterpret_cast<const short8*>(aptr + k0);
    short8 bv = *reinterpret_cast<const short8*>(bptr + k0);
    __syncthreads();
    *reinterpret_cast<short8*>(&As[srow * LDT + scol]) = av;
    *reinterpret_cast<short8*>(&Bs[srow * LDT + scol]) = bv;
    __syncthreads();
    short8 af[2], bfr[2];
#pragma unroll
    for (int f = 0; f < 2; ++f) {
      af[f]  = *reinterpret_cast<const short8*>(&As[(wm * 32 + f * 16 + l15) * LDT + lhi * 8]);
      bfr[f] = *reinterpret_cast<const short8*>(&Bs[(wn * 32 + f * 16 + l15) * LDT + lhi * 8]);
    }
#pragma unroll
    for (int i = 0; i < 2; ++i)
#pragma unroll
      for (int j = 0; j < 2; ++j)
        acc[i][j] = __builtin_amdgcn_mfma_f32_16x16x32_bf16(af[i], bfr[j], acc[i][j], 0, 0, 0);
  }

#pragma unroll
  for (int i = 0; i < 2; ++i)
#pragma unroll
    for (int j = 0; j < 2; ++j) {
      int row = m0 + wm * 32 + i * 16 + lhi * 4;
      int col = n0 + wn * 32 + j * 16 + l15;
      float bv = bias[col];
#pragma unroll
      for (int r = 0; r < 4; ++r) {
        float v = acc[i][j][r] + bv;
        if (OUTF32) reinterpret_cast<float*>(Cout)[(size_t)(row + r) * N + col] = v;
        else        reinterpret_cast<u16*>(Cout)[(size_t)(row + r) * N + col] = f2bf(v);
      }
    }
}

// ---------------- V transpose: qkv V-part -> vt[(b*12+h)*64 + d][s] ----------------
__global__ __launch_bounds__(256) void vtrans_kernel(
    const u16* __restrict__ qkv, u16* __restrict__ vt)
{
  __shared__ u16 T[64][72];
  const int idx = blockIdx.x;
  const int st = idx & 15;           // s-tile (16 of 64 rows)
  const int bh = idx >> 4;           // 0..191
  const int b = bh / 12, h = bh % 12;
  const int t = threadIdx.x;
  const int r2 = t >> 3, c8 = (t & 7) * 8;

  const u16* src = qkv + ((size_t)(b * 1024 + st * 64)) * 2304 + 1536 + h * 64;
#pragma unroll
  for (int rr = 0; rr < 2; ++rr) {
    int s = rr * 32 + r2;
    short8 v = *reinterpret_cast<const short8*>(src + (size_t)s * 2304 + c8);
    *reinterpret_cast<short8*>(&T[s][c8]) = v;
  }
  __syncthreads();
  u16* dst = vt + (size_t)bh * 64 * 1024 + st * 64;
#pragma unroll
  for (int rr = 0; rr < 2; ++rr) {
    int d = rr * 32 + r2;
    short8 o;
#pragma unroll
    for (int j = 0; j < 8; ++j) o[j] = T[c8 + j][d];
    *reinterpret_cast<short8*>(dst + (size_t)d * 1024 + c8) = o;
  }
}

// ---------------- fused flash attention, swapped QK^T, 32x32x16 MFMA ----------------
// Block: (b, h, 128-q-row tile), 4 waves x 32 q-rows. KV tiles of 64.
// Swapped QK^T: D = mfma(K, Q) -> D(row=key, col=q): lane&31 = q, lane pair
// (l, l+32) holds all 64 keys of the tile (32 f32 regs each). Softmax is
// in-register + one shfl_xor(32). P -> PV A-frag via cvt_pk + shfl_xor(32).
__global__ __launch_bounds__(256) void attn2_kernel(
    const u16* __restrict__ qkv, const u16* __restrict__ vt, u16* __restrict__ z)
{
  constexpr int LDK = 72;
  __shared__ u16 Ks[64 * LDK];   // [key][d]
  __shared__ u16 Vs[64 * LDK];   // [d][key]  (from pre-transposed vt)

  const int tid = threadIdx.x;
  const int lane = tid & 63, w = tid >> 6;
  const int l31 = lane & 31, hi = lane >> 5;

  const int idx = blockIdx.x;
  const int qt = idx & 7;           // 8 q-tiles of 128
  const int h  = (idx >> 3) % 12;
  const int b  = idx / 96;
  const int bh = b * 12 + h;

  const size_t rowbase = (size_t)b * 1024;
  const u16* Qp  = qkv + rowbase * 2304 + h * 64;
  const u16* Kp  = Qp + 768;
  const u16* Vtp = vt + (size_t)bh * 64 * 1024;

  const int q0 = qt * 128 + w * 32;

  // Q as B-frag: lane&31 = q, k = c*16 + hi*8 + e
  short8 qf[4];
#pragma unroll
  for (int c = 0; c < 4; ++c)
    qf[c] = *reinterpret_cast<const short8*>(
        Qp + (size_t)(q0 + l31) * 2304 + c * 16 + hi * 8);

  floatx16 oacc0 = {}, oacc1 = {};   // O for d-blocks 0..31 / 32..63
  float m_run = -1e30f, l_run = 0.f;
  constexpr float C = 0.180336880f;     // 0.125 * log2(e)
  constexpr float THRraw = 8.0f / C;    // defer-max threshold (p <= 2^8)

  const int srow = tid >> 3, scol = (tid & 7) * 8;

  for (int kt = 0; kt < 16; ++kt) {
    const int kv0 = kt * 64;
    __syncthreads();
#pragma unroll
    for (int rr = 0; rr < 2; ++rr) {
      int row = rr * 32 + srow;
      short8 kv = *reinterpret_cast<const short8*>(Kp + (size_t)(kv0 + row) * 2304 + scol);
      short8 vv = *reinterpret_cast<const short8*>(Vtp + (size_t)row * 1024 + kv0 + scol);
      *reinterpret_cast<short8*>(&Ks[row * LDK + scol]) = kv;
      *reinterpret_cast<short8*>(&Vs[row * LDK + scol]) = vv;
    }
    __syncthreads();

    // S(key, q) for key-blocks 0 and 1
    floatx16 s0 = {}, s1 = {};
#pragma unroll
    for (int c = 0; c < 4; ++c) {
      short8 kf0 = *reinterpret_cast<const short8*>(&Ks[(l31)      * LDK + c * 16 + hi * 8]);
      short8 kf1 = *reinterpret_cast<const short8*>(&Ks[(32 + l31) * LDK + c * 16 + hi * 8]);
      s0 = __builtin_amdgcn_mfma_f32_32x32x16_bf16(kf0, qf[c], s0, 0, 0, 0);
      s1 = __builtin_amdgcn_mfma_f32_32x32x16_bf16(kf1, qf[c], s1, 0, 0, 0);
    }

    // tile max for this lane's q-row (own 32 keys + partner half)
    float pmax = s0[0];
#pragma unroll
    for (int r = 1; r < 16; ++r) pmax = fmaxf(pmax, s0[r]);
#pragma unroll
    for (int r = 0; r < 16; ++r) pmax = fmaxf(pmax, s1[r]);
    pmax = fmaxf(pmax, __shfl_xor(pmax, 32, 64));

    float m_use = m_run;
    if (!__all(pmax - m_run <= THRraw)) {
      float mnew = fmaxf(m_run, pmax);
      float alpha = exp2f((m_run - mnew) * C);
#pragma unroll
      for (int r = 0; r < 16; ++r) {
        int q = (r & 3) + 8 * (r >> 2) + 4 * hi;
        float al = __uint_as_float(
            __builtin_amdgcn_ds_bpermute(((lane & 32) + q) * 4, __float_as_uint(alpha)));
        oacc0[r] *= al;
        oacc1[r] *= al;
      }
      l_run *= alpha;
      m_run = mnew;
      m_use = mnew;
    }

    // exp + sum (raw scores; scale folded into exp2 factor C)
    float tsum = 0.f;
#pragma unroll
    for (int r = 0; r < 16; ++r) {
      float e0 = exp2f((s0[r] - m_use) * C);
      float e1 = exp2f((s1[r] - m_use) * C);
      s0[r] = e0; s1[r] = e1;
      tsum += e0 + e1;
    }
    tsum += __shfl_xor(tsum, 32, 64);
    l_run += tsum;

    // P -> bf16 A-frags: chunk c keys c*16 + hi*8 + e.
    // Owner regs for dest-half hd: block B = ((c&1)*2 + hd)*4 in BOTH halves.
    short8 pa[4];
#pragma unroll
    for (int c = 0; c < 4; ++c) {
      const floatx16& sv = (c >> 1) ? s1 : s0;
      const int B0 = (c & 1) * 8, B1 = B0 + 4;
      unsigned a0 = cvt_pk_bf16(sv[B0],     sv[B0 + 1]);
      unsigned a1 = cvt_pk_bf16(sv[B0 + 2], sv[B0 + 3]);
      unsigned b0 = cvt_pk_bf16(sv[B1],     sv[B1 + 1]);
      unsigned b1 = cvt_pk_bf16(sv[B1 + 2], sv[B1 + 3]);
      unsigned send0 = hi ? a0 : b0, send1 = hi ? a1 : b1;   // partner's block B(1-their hi)
      unsigned keep0 = hi ? b0 : a0, keep1 = hi ? b1 : a1;   // own block B(hi)
      unsigned r0 = (unsigned)__shfl_xor((int)send0, 32, 64);
      unsigned r1 = (unsigned)__shfl_xor((int)send1, 32, 64);
      union { unsigned u[4]; short8 v; } P;
      P.u[0] = hi ? r0 : keep0;
      P.u[1] = hi ? r1 : keep1;
      P.u[2] = hi ? keep0 : r0;
      P.u[3] = hi ? keep1 : r1;
      pa[c] = P.v;
    }

    // O += P @ V   (B-frag from transposed V: lane&31 = d, k = c*16 + hi*8 + e)
#pragma unroll
    for (int c = 0; c < 4; ++c) {
      short8 vf0 = *reinterpret_cast<const short8*>(&Vs[(l31)      * LDK + c * 16 + hi * 8]);
      short8 vf1 = *reinterpret_cast<const short8*>(&Vs[(32 + l31) * LDK + c * 16 + hi * 8]);
      oacc0 = __builtin_amdgcn_mfma_f32_32x32x16_bf16(pa[c], vf0, oacc0, 0, 0, 0);
      oacc1 = __builtin_amdgcn_mfma_f32_32x32x16_bf16(pa[c], vf1, oacc1, 0, 0, 0);
    }
  }

  // normalize + store: lane holds d = db*32 + l31, q = (r&3)+8*(r>>2)+4*hi
  float linv = 1.0f / l_run;
#pragma unroll
  for (int r = 0; r < 16; ++r) {
    int q = (r & 3) + 8 * (r >> 2) + 4 * hi;
    float li = __uint_as_float(
        __builtin_amdgcn_ds_bpermute(((lane & 32) + q) * 4, __float_as_uint(linv)));
    size_t orow = (rowbase + q0 + q) * (size_t)768 + h * 64;
    z[orow + l31]      = f2bf(oacc0[r] * li);
    z[orow + 32 + l31] = f2bf(oacc1[r] * li);
  }
}

extern "C" void kernel_launch(void* const* d_in, const int* in_sizes, int n_in,
                              void* d_out, int out_size, void* d_ws, size_t ws_size,
                              hipStream_t stream) {
  (void)in_sizes; (void)n_in; (void)out_size; (void)ws_size;
  const float* x      = (const float*)d_in[0];
  const float* w_qkv  = (const float*)d_in[1];
  const float* b_qkv  = (const float*)d_in[2];
  const float* w_proj = (const float*)d_in[3];
  const float* b_proj = (const float*)d_in[4];
  float* out = (float*)d_out;

  const int BS = 16 * 1024;  // B*S rows
  const int D = 768, N3 = 2304;

  // workspace layout (bf16 buffers)
  u16* xb  = (u16*)d_ws;                     // [BS, D]     (reused as vt after gemm1)
  u16* wqb = xb  + (size_t)BS * D;           // [N3, D]
  u16* wpb = wqb + (size_t)N3 * D;           // [D, D]
  u16* qkv = wpb + (size_t)D * D;            // [BS, N3]
  u16* zb  = qkv + (size_t)BS * N3;          // [BS, D]
  u16* vtb = xb;                             // [192*64, 1024] == BS*D elems, aliases xb

  cvt_kernel<<<2048, 256, 0, stream>>>(x, xb, BS * D / 4);
  cvt_kernel<<<512, 256, 0, stream>>>(w_qkv, wqb, N3 * D / 4);
  cvt_kernel<<<256, 256, 0, stream>>>(w_proj, wpb, D * D / 4);

  gemm_bt<false><<<dim3(BS / 64, N3 / 64), 256, 0, stream>>>(xb, wqb, b_qkv, qkv, BS, N3, D);
  vtrans_kernel<<<192 * 16, 256, 0, stream>>>(qkv, vtb);
  attn2_kernel<<<16 * 12 * 8, 256, 0, stream>>>(qkv, vtb, zb);
  gemm_bt<true><<<dim3(BS / 64, D / 64), 256, 0, stream>>>(zb, wpb, b_proj, out, BS, D, D);
}

// Round 3
// 285.391 us; speedup vs baseline: 1.5170x; 1.1587x over previous
//
#include <hip/hip_runtime.h>
#include <hip/hip_bf16.h>
#include <cstdint>
#include <cstddef>

typedef __attribute__((ext_vector_type(8))) short short8;
typedef __attribute__((ext_vector_type(4))) float floatx4;
typedef __attribute__((ext_vector_type(16))) float floatx16;
typedef unsigned short u16;

__device__ __forceinline__ u16 f2bf(float f) {
  unsigned u = __float_as_uint(f);
  u += 0x7FFFu + ((u >> 16) & 1u);
  return (u16)(u >> 16);
}

__device__ __forceinline__ unsigned cvt_pk_bf16(float a, float b) {
  unsigned r;
  asm("v_cvt_pk_bf16_f32 %0, %1, %2" : "=v"(r) : "v"(a), "v"(b));
  return r;
}

// async global -> LDS, 16B per lane. LDS dest = wave-uniform base + lane*16.
__device__ __forceinline__ void gload16(const u16* g, u16* l) {
  __builtin_amdgcn_global_load_lds(
      (const __attribute__((address_space(1))) void*)g,
      (__attribute__((address_space(3))) void*)l, 16, 0, 0);
}

// ---------------- f32 -> bf16 convert (vectorized) ----------------
__global__ void cvt_kernel(const float* __restrict__ in, u16* __restrict__ out, int n4) {
  int i = blockIdx.x * blockDim.x + threadIdx.x;
  int stride = gridDim.x * blockDim.x;
  for (int idx = i; idx < n4; idx += stride) {
    float4 v = reinterpret_cast<const float4*>(in)[idx];
    ushort4 o = make_ushort4(f2bf(v.x), f2bf(v.y), f2bf(v.z), f2bf(v.w));
    reinterpret_cast<ushort4*>(out)[idx] = o;
  }
}

// ---------------- C = A @ B^T + bias, 128x128 tile (m97 structure) ----------------
// A[M,K], B[N,K] bf16 row-major. 4 waves 2x2, each computes 64x64 (acc[4][4]).
// BK=32. LDS linear [128][32] (global_load_lds). Bijective XCD swizzle (nwg%8==0).
template<bool OUTF32>
__global__ __launch_bounds__(256) void gemm_bt128(
    const u16* __restrict__ A, const u16* __restrict__ B,
    const float* __restrict__ bias, void* __restrict__ Cout,
    int M, int N, int K)
{
  __shared__ u16 As[128 * 32];
  __shared__ u16 Bs[128 * 32];
  const int tid = threadIdx.x;
  const int lane = tid & 63, w = tid >> 6;
  const int l15 = lane & 15, lhi = lane >> 4;
  const int wm = w >> 1, wn = w & 1;

  const int mblocks = M >> 7;
  const int cpx = gridDim.x >> 3;
  const int bid = blockIdx.x;
  const int swz = (bid & 7) * cpx + (bid >> 3);
  const int m0 = (swz % mblocks) << 7;
  const int n0 = (swz / mblocks) << 7;

  const int srow = tid >> 2;          // 0..63
  const int scol = (tid & 3) * 8;     // element offset within row
  const u16* aptr = A + (size_t)(m0 + srow) * K + scol;
  const u16* bptr = B + (size_t)(n0 + srow) * K + scol;
  const size_t r64 = (size_t)64 * K;

  // per-wave LDS bases (elements): inst i covers rows i*64+(tid>>2)
  u16* asd0 = As + w * 512;
  u16* asd1 = As + 2048 + w * 512;
  u16* bsd0 = Bs + w * 512;
  u16* bsd1 = Bs + 2048 + w * 512;

  floatx4 acc[4][4] = {};

  for (int k0 = 0; k0 < K; k0 += 32) {
    __syncthreads();               // previous compute done reading LDS
    gload16(aptr + k0,       asd0);
    gload16(aptr + k0 + r64, asd1);
    gload16(bptr + k0,       bsd0);
    gload16(bptr + k0 + r64, bsd1);
    __syncthreads();               // drains vmcnt -> tiles resident

    short8 af[4], bf[4];
#pragma unroll
    for (int i = 0; i < 4; ++i) {
      af[i] = *reinterpret_cast<const short8*>(&As[(wm * 64 + i * 16 + l15) * 32 + lhi * 8]);
      bf[i] = *reinterpret_cast<const short8*>(&Bs[(wn * 64 + i * 16 + l15) * 32 + lhi * 8]);
    }
#pragma unroll
    for (int i = 0; i < 4; ++i)
#pragma unroll
      for (int j = 0; j < 4; ++j)
        acc[i][j] = __builtin_amdgcn_mfma_f32_16x16x32_bf16(af[i], bf[j], acc[i][j], 0, 0, 0);
  }

#pragma unroll
  for (int i = 0; i < 4; ++i)
#pragma unroll
    for (int j = 0; j < 4; ++j) {
      int row = m0 + wm * 64 + i * 16 + lhi * 4;
      int col = n0 + wn * 64 + j * 16 + l15;
      float bv = bias[col];
#pragma unroll
      for (int r = 0; r < 4; ++r) {
        float v = acc[i][j][r] + bv;
        if (OUTF32) reinterpret_cast<float*>(Cout)[(size_t)(row + r) * N + col] = v;
        else        reinterpret_cast<u16*>(Cout)[(size_t)(row + r) * N + col] = f2bf(v);
      }
    }
}

// ---------------- V transpose: qkv V-part -> vt[(b*12+h)*64 + d][s] ----------------
__global__ __launch_bounds__(256) void vtrans_kernel(
    const u16* __restrict__ qkv, u16* __restrict__ vt)
{
  __shared__ u16 T[64][72];
  const int idx = blockIdx.x;
  const int st = idx & 15;           // s-tile (16 of 64 rows)
  const int bh = idx >> 4;           // 0..191
  const int b = bh / 12, h = bh % 12;
  const int t = threadIdx.x;
  const int r2 = t >> 3, c8 = (t & 7) * 8;

  const u16* src = qkv + ((size_t)(b * 1024 + st * 64)) * 2304 + 1536 + h * 64;
#pragma unroll
  for (int rr = 0; rr < 2; ++rr) {
    int s = rr * 32 + r2;
    short8 v = *reinterpret_cast<const short8*>(src + (size_t)s * 2304 + c8);
    *reinterpret_cast<short8*>(&T[s][c8]) = v;
  }
  __syncthreads();
  u16* dst = vt + (size_t)bh * 64 * 1024 + st * 64;
#pragma unroll
  for (int rr = 0; rr < 2; ++rr) {
    int d = rr * 32 + r2;
    short8 o;
#pragma unroll
    for (int j = 0; j < 8; ++j) o[j] = T[c8 + j][d];
    *reinterpret_cast<short8*>(dst + (size_t)d * 1024 + c8) = o;
  }
}

// ---------------- fused flash attention, swapped QK^T, 32x32x16 MFMA ----------------
__global__ __launch_bounds__(256) void attn2_kernel(
    const u16* __restrict__ qkv, const u16* __restrict__ vt, u16* __restrict__ z)
{
  constexpr int LDK = 72;
  __shared__ u16 Ks[64 * LDK];   // [key][d]
  __shared__ u16 Vs[64 * LDK];   // [d][key]  (from pre-transposed vt)

  const int tid = threadIdx.x;
  const int lane = tid & 63, w = tid >> 6;
  const int l31 = lane & 31, hi = lane >> 5;

  const int idx = blockIdx.x;
  const int qt = idx & 7;           // 8 q-tiles of 128
  const int h  = (idx >> 3) % 12;
  const int b  = idx / 96;
  const int bh = b * 12 + h;

  const size_t rowbase = (size_t)b * 1024;
  const u16* Qp  = qkv + rowbase * 2304 + h * 64;
  const u16* Kp  = Qp + 768;
  const u16* Vtp = vt + (size_t)bh * 64 * 1024;

  const int q0 = qt * 128 + w * 32;

  short8 qf[4];
#pragma unroll
  for (int c = 0; c < 4; ++c)
    qf[c] = *reinterpret_cast<const short8*>(
        Qp + (size_t)(q0 + l31) * 2304 + c * 16 + hi * 8);

  floatx16 oacc0 = {}, oacc1 = {};
  float m_run = -1e30f, l_run = 0.f;
  constexpr float C = 0.180336880f;     // 0.125 * log2(e)
  constexpr float THRraw = 8.0f / C;

  const int srow = tid >> 3, scol = (tid & 7) * 8;

  for (int kt = 0; kt < 16; ++kt) {
    const int kv0 = kt * 64;
    __syncthreads();
#pragma unroll
    for (int rr = 0; rr < 2; ++rr) {
      int row = rr * 32 + srow;
      short8 kv = *reinterpret_cast<const short8*>(Kp + (size_t)(kv0 + row) * 2304 + scol);
      short8 vv = *reinterpret_cast<const short8*>(Vtp + (size_t)row * 1024 + kv0 + scol);
      *reinterpret_cast<short8*>(&Ks[row * LDK + scol]) = kv;
      *reinterpret_cast<short8*>(&Vs[row * LDK + scol]) = vv;
    }
    __syncthreads();

    floatx16 s0 = {}, s1 = {};
#pragma unroll
    for (int c = 0; c < 4; ++c) {
      short8 kf0 = *reinterpret_cast<const short8*>(&Ks[(l31)      * LDK + c * 16 + hi * 8]);
      short8 kf1 = *reinterpret_cast<const short8*>(&Ks[(32 + l31) * LDK + c * 16 + hi * 8]);
      s0 = __builtin_amdgcn_mfma_f32_32x32x16_bf16(kf0, qf[c], s0, 0, 0, 0);
      s1 = __builtin_amdgcn_mfma_f32_32x32x16_bf16(kf1, qf[c], s1, 0, 0, 0);
    }

    float pmax = s0[0];
#pragma unroll
    for (int r = 1; r < 16; ++r) pmax = fmaxf(pmax, s0[r]);
#pragma unroll
    for (int r = 0; r < 16; ++r) pmax = fmaxf(pmax, s1[r]);
    pmax = fmaxf(pmax, __shfl_xor(pmax, 32, 64));

    float m_use = m_run;
    if (!__all(pmax - m_run <= THRraw)) {
      float mnew = fmaxf(m_run, pmax);
      float alpha = exp2f((m_run - mnew) * C);
#pragma unroll
      for (int r = 0; r < 16; ++r) {
        int q = (r & 3) + 8 * (r >> 2) + 4 * hi;
        float al = __uint_as_float(
            __builtin_amdgcn_ds_bpermute(((lane & 32) + q) * 4, __float_as_uint(alpha)));
        oacc0[r] *= al;
        oacc1[r] *= al;
      }
      l_run *= alpha;
      m_run = mnew;
      m_use = mnew;
    }

    float tsum = 0.f;
#pragma unroll
    for (int r = 0; r < 16; ++r) {
      float e0 = exp2f((s0[r] - m_use) * C);
      float e1 = exp2f((s1[r] - m_use) * C);
      s0[r] = e0; s1[r] = e1;
      tsum += e0 + e1;
    }
    tsum += __shfl_xor(tsum, 32, 64);
    l_run += tsum;

    short8 pa[4];
#pragma unroll
    for (int c = 0; c < 4; ++c) {
      const floatx16& sv = (c >> 1) ? s1 : s0;
      const int B0 = (c & 1) * 8, B1 = B0 + 4;
      unsigned a0 = cvt_pk_bf16(sv[B0],     sv[B0 + 1]);
      unsigned a1 = cvt_pk_bf16(sv[B0 + 2], sv[B0 + 3]);
      unsigned b0 = cvt_pk_bf16(sv[B1],     sv[B1 + 1]);
      unsigned b1 = cvt_pk_bf16(sv[B1 + 2], sv[B1 + 3]);
      unsigned send0 = hi ? a0 : b0, send1 = hi ? a1 : b1;
      unsigned keep0 = hi ? b0 : a0, keep1 = hi ? b1 : a1;
      unsigned r0 = (unsigned)__shfl_xor((int)send0, 32, 64);
      unsigned r1 = (unsigned)__shfl_xor((int)send1, 32, 64);
      union { unsigned u[4]; short8 v; } P;
      P.u[0] = hi ? r0 : keep0;
      P.u[1] = hi ? r1 : keep1;
      P.u[2] = hi ? keep0 : r0;
      P.u[3] = hi ? keep1 : r1;
      pa[c] = P.v;
    }

#pragma unroll
    for (int c = 0; c < 4; ++c) {
      short8 vf0 = *reinterpret_cast<const short8*>(&Vs[(l31)      * LDK + c * 16 + hi * 8]);
      short8 vf1 = *reinterpret_cast<const short8*>(&Vs[(32 + l31) * LDK + c * 16 + hi * 8]);
      oacc0 = __builtin_amdgcn_mfma_f32_32x32x16_bf16(pa[c], vf0, oacc0, 0, 0, 0);
      oacc1 = __builtin_amdgcn_mfma_f32_32x32x16_bf16(pa[c], vf1, oacc1, 0, 0, 0);
    }
  }

  float linv = 1.0f / l_run;
#pragma unroll
  for (int r = 0; r < 16; ++r) {
    int q = (r & 3) + 8 * (r >> 2) + 4 * hi;
    float li = __uint_as_float(
        __builtin_amdgcn_ds_bpermute(((lane & 32) + q) * 4, __float_as_uint(linv)));
    size_t orow = (rowbase + q0 + q) * (size_t)768 + h * 64;
    z[orow + l31]      = f2bf(oacc0[r] * li);
    z[orow + 32 + l31] = f2bf(oacc1[r] * li);
  }
}

extern "C" void kernel_launch(void* const* d_in, const int* in_sizes, int n_in,
                              void* d_out, int out_size, void* d_ws, size_t ws_size,
                              hipStream_t stream) {
  (void)in_sizes; (void)n_in; (void)out_size; (void)ws_size;
  const float* x      = (const float*)d_in[0];
  const float* w_qkv  = (const float*)d_in[1];
  const float* b_qkv  = (const float*)d_in[2];
  const float* w_proj = (const float*)d_in[3];
  const float* b_proj = (const float*)d_in[4];
  float* out = (float*)d_out;

  const int BS = 16 * 1024;  // B*S rows
  const int D = 768, N3 = 2304;

  u16* xb  = (u16*)d_ws;                     // [BS, D]   (reused as vt after gemm1)
  u16* wqb = xb  + (size_t)BS * D;           // [N3, D]
  u16* wpb = wqb + (size_t)N3 * D;           // [D, D]
  u16* qkv = wpb + (size_t)D * D;            // [BS, N3]
  u16* zb  = qkv + (size_t)BS * N3;          // [BS, D]
  u16* vtb = xb;                             // aliases xb

  cvt_kernel<<<2048, 256, 0, stream>>>(x, xb, BS * D / 4);
  cvt_kernel<<<512, 256, 0, stream>>>(w_qkv, wqb, N3 * D / 4);
  cvt_kernel<<<256, 256, 0, stream>>>(w_proj, wpb, D * D / 4);

  gemm_bt128<false><<<(BS / 128) * (N3 / 128), 256, 0, stream>>>(xb, wqb, b_qkv, qkv, BS, N3, D);
  vtrans_kernel<<<192 * 16, 256, 0, stream>>>(qkv, vtb);
  attn2_kernel<<<16 * 12 * 8, 256, 0, stream>>>(qkv, vtb, zb);
  gemm_bt128<true><<<(BS / 128) * (D / 128), 256, 0, stream>>>(zb, wpb, b_proj, out, BS, D, D);
}